// Round 2
// baseline (311.114 us; speedup 1.0000x reference)
//
#include <hip/hip_runtime.h>
#include <math.h>

#define NB    256
#define NC    3
#define NH    224
#define NW    224
#define SAMPLE_ELEMS (NC * NH * NW)            // 150528
#define SAMPLE_V4    (SAMPLE_ELEMS / 4)        // 37632
#define W4 (NW / 4)                            // 56
#define THREADS 1024

// One block per sample: phase 1 computes the per-sample sum (needed for the
// contrast mean), phase 2 re-reads the same 588 KB (hot in L2/L3) and applies
// flip + fused affine (brightness*contrast + mean offset) + erase + clip.
// No grid sync, no separate params kernel, no inter-kernel drains.
__global__ __launch_bounds__(THREADS) void fused_aug_kernel(
        const float4* __restrict__ x,
        const float* __restrict__ flip_u,
        const float* __restrict__ bright_u,
        const float* __restrict__ bright_v,
        const float* __restrict__ contrast_u,
        const float* __restrict__ contrast_v,
        const float* __restrict__ erase_u,
        const float* __restrict__ erase_box,
        float4* __restrict__ out) {
    const int b = blockIdx.x;
    const float4* __restrict__ xs = x + (size_t)b * SAMPLE_V4;
    float4* __restrict__       os = out + (size_t)b * SAMPLE_V4;

    // ---- phase 1: sample sum (2-way unrolled independent loads for ILP) ----
    float s0 = 0.0f, s1 = 0.0f;
    int k = threadIdx.x;
    for (; k + THREADS < SAMPLE_V4; k += 2 * THREADS) {
        float4 a = xs[k];
        float4 c = xs[k + THREADS];
        s0 += (a.x + a.y) + (a.z + a.w);
        s1 += (c.x + c.y) + (c.z + c.w);
    }
    if (k < SAMPLE_V4) {                       // at most one leftover per thread
        float4 a = xs[k];
        s0 += (a.x + a.y) + (a.z + a.w);
    }
    float s = s0 + s1;

    #pragma unroll
    for (int off = 32; off > 0; off >>= 1) s += __shfl_down(s, off, 64);

    __shared__ float red[16];
    __shared__ float mean_sh;
    const int lane = threadIdx.x & 63;
    const int wid  = threadIdx.x >> 6;
    if (lane == 0) red[wid] = s;
    __syncthreads();
    if (threadIdx.x == 0) {
        float t = 0.0f;
        #pragma unroll
        for (int i = 0; i < 16; ++i) t += red[i];
        mean_sh = t / (float)SAMPLE_ELEMS;
    }
    __syncthreads();

    // ---- per-sample params (scalar broadcast loads, all lanes uniform) ----
    const float bsc  = (bright_u[b] < 0.7f) ? (0.8f + 0.4f * bright_v[b]) : 1.0f;
    const float mean = mean_sh * bsc;          // mean of post-brightness image
    float csc = 1.0f, t = 0.0f;
    if (contrast_u[b] < 0.7f) {
        csc = 0.8f + 0.4f * contrast_v[b];
        t   = mean * (1.0f - csc);             // (x-m)*c + m == x*c + m*(1-c)
    }
    const float scale = bsc * csc;
    const int   flip  = (flip_u[b] < 0.5f) ? 1 : 0;
    const int   em    = (erase_u[b] < 0.3f) ? 1 : 0;

    // replicate reference f32 floor arithmetic exactly
    const float u0 = erase_box[b * 4 + 0];
    const float u1 = erase_box[b * 4 + 1];
    const float u2 = erase_box[b * 4 + 2];
    const float u3 = erase_box[b * 4 + 3];
    const int eh = (int)floorf((float)NH * (0.02f + 0.18f * u0));
    const int ew = (int)floorf((float)NW * (0.02f + 0.18f * u1));
    const int ph = (int)floorf((float)(NH - eh) * u2);
    const int pw = (int)floorf((float)(NW - ew) * u3);
    const int ph_end = ph + eh;
    const int pw_end = pw + ew;

    // ---- phase 2: apply (reads are L2/L3-hot from phase 1) ----
    for (int i = threadIdx.x; i < SAMPLE_V4; i += THREADS) {
        const int w4  = i % W4;
        const int row = i / W4;                // c*NH + h
        const int h   = row % NH;
        const int w0  = w4 * 4;

        float4 v;
        if (flip) {
            const float4 r = xs[row * W4 + (W4 - 1 - w4)];
            v = make_float4(r.w, r.z, r.y, r.x);
        } else {
            v = xs[i];
        }

        float o0 = v.x * scale + t;
        float o1 = v.y * scale + t;
        float o2 = v.z * scale + t;
        float o3 = v.w * scale + t;

        if (em && h >= ph && h < ph_end) {
            if (w0     >= pw && w0     < pw_end) o0 = 0.0f;
            if (w0 + 1 >= pw && w0 + 1 < pw_end) o1 = 0.0f;
            if (w0 + 2 >= pw && w0 + 2 < pw_end) o2 = 0.0f;
            if (w0 + 3 >= pw && w0 + 3 < pw_end) o3 = 0.0f;
        }

        o0 = fminf(fmaxf(o0, 0.0f), 1.0f);
        o1 = fminf(fmaxf(o1, 0.0f), 1.0f);
        o2 = fminf(fmaxf(o2, 0.0f), 1.0f);
        o3 = fminf(fmaxf(o3, 0.0f), 1.0f);

        os[i] = make_float4(o0, o1, o2, o3);
    }
}

extern "C" void kernel_launch(void* const* d_in, const int* in_sizes, int n_in,
                              void* d_out, int out_size, void* d_ws, size_t ws_size,
                              hipStream_t stream) {
    const float* x          = (const float*)d_in[0];
    const float* flip_u     = (const float*)d_in[1];
    const float* bright_u   = (const float*)d_in[2];
    const float* bright_v   = (const float*)d_in[3];
    const float* contrast_u = (const float*)d_in[4];
    const float* contrast_v = (const float*)d_in[5];
    const float* erase_u    = (const float*)d_in[6];
    const float* erase_box  = (const float*)d_in[7];

    fused_aug_kernel<<<NB, THREADS, 0, stream>>>(
        (const float4*)x, flip_u, bright_u, bright_v,
        contrast_u, contrast_v, erase_u, erase_box, (float4*)d_out);
}